// Round 1
// baseline (25136.079 us; speedup 1.0000x reference)
//
#include <hip/hip_runtime.h>
#include <stdint.h>

// ---------------------------------------------------------------------------
// MoERNN: router -> 4 expert BiLSTMs (fused persistent kernel) -> gated
// combine -> output GEMM.  All heavy math in bf16 MFMA, fp32 accumulate.
// ---------------------------------------------------------------------------

typedef __attribute__((ext_vector_type(8)))  short short8;
typedef __attribute__((ext_vector_type(4)))  float float4v;
typedef __attribute__((ext_vector_type(16))) float float16v;

__device__ __forceinline__ unsigned short f2bf(float x) {
  union { float f; unsigned int u; } v; v.f = x;
  unsigned int r = v.u + 0x7fffu + ((v.u >> 16) & 1u);   // RNE
  return (unsigned short)(r >> 16);
}
__device__ __forceinline__ float bf2f(unsigned short h) {
  union { unsigned int u; float f; } v; v.u = ((unsigned int)h) << 16;
  return v.f;
}

// ---------------- conversion / permutation kernels -------------------------

// x [32][512][512] f32  ->  xT [t][b][i] bf16
__global__ void cx_kernel(const float* __restrict__ x, unsigned short* __restrict__ xT) {
  int idx = blockIdx.x * 256 + threadIdx.x;        // 1,048,576 total
  int i8 = idx & 63, b = (idx >> 6) & 31, t = idx >> 11;
  const float* src = x + ((size_t)(b * 512 + t) * 512 + i8 * 8);
  short8 v;
#pragma unroll
  for (int k = 0; k < 8; ++k) v[k] = (short)f2bf(src[k]);
  *(short8*)(xT + ((size_t)(t * 32 + b) * 512 + i8 * 8)) = v;
}

// W [8][2048][512] f32 -> Wp [chain][slice][n_local = jl*4+g][512] bf16
__global__ void cw_kernel(const float* __restrict__ W, unsigned short* __restrict__ Wp) {
  int idx = blockIdx.x * 256 + threadIdx.x;        // 1,048,576 total
  int k8 = idx & 63, nl = (idx >> 6) & 63, sl = (idx >> 12) & 31, c = idx >> 17;
  int jl = nl >> 2, g = nl & 3;
  int row = g * 512 + sl * 16 + jl;
  const float* src = W + ((size_t)(c * 2048 + row) * 512 + k8 * 8);
  short8 v;
#pragma unroll
  for (int k = 0; k < 8; ++k) v[k] = (short)f2bf(src[k]);
  *(short8*)(Wp + ((size_t)((c * 32 + sl) * 64 + nl) * 512 + k8 * 8)) = v;
}

// Wout [512][1024] f32 -> bf16
__global__ void cwout_kernel(const float* __restrict__ W, unsigned short* __restrict__ Wb) {
  int idx = blockIdx.x * 256 + threadIdx.x;        // 65,536 total
  const float* src = W + (size_t)idx * 8;
  short8 v;
#pragma unroll
  for (int k = 0; k < 8; ++k) v[k] = (short)f2bf(src[k]);
  *(short8*)(Wb + (size_t)idx * 8) = v;
}

// bias_p[(c*32+sl)*64 + nl] = bih + bhh (permuted like Wp rows)
__global__ void cbias_kernel(const float* __restrict__ bih, const float* __restrict__ bhh,
                             float* __restrict__ bias_p) {
  int idx = blockIdx.x * 256 + threadIdx.x;        // 16,384 total
  int nl = idx & 63, sl = (idx >> 6) & 31, c = idx >> 11;
  int jl = nl >> 2, g = nl & 3;
  int row = g * 512 + sl * 16 + jl;
  bias_p[idx] = bih[c * 2048 + row] + bhh[c * 2048 + row];
}

// ---------------- router ----------------------------------------------------

__global__ void r1_kernel(const float* __restrict__ x, float* __restrict__ rin) {
  int b = blockIdx.x >> 1, half = blockIdx.x & 1;
  int i = half * 256 + threadIdx.x;
  float s = 0.f;
  for (int t = 0; t < 512; ++t) s += x[(size_t)(b * 512 + t) * 512 + i];
  rin[b * 512 + i] = s * (1.f / 512.f);
}

__global__ __launch_bounds__(256) void r2_kernel(
    const float* __restrict__ rin, const float* __restrict__ rW1, const float* __restrict__ rb1,
    const float* __restrict__ rW2, const float* __restrict__ rb2,
    float* __restrict__ gate, float* __restrict__ probs) {
  __shared__ float srin[512];
  __shared__ float sh1[512];
  __shared__ float red[256];
  __shared__ float lg[4];
  int b = blockIdx.x, tid = threadIdx.x;
  srin[tid] = rin[b * 512 + tid];
  srin[tid + 256] = rin[b * 512 + tid + 256];
  __syncthreads();
  for (int rep = 0; rep < 2; ++rep) {
    int jj = tid + rep * 256;
    float acc = rb1[jj];
    const float4v* w  = (const float4v*)(rW1 + (size_t)jj * 512);
    const float4v* r4 = (const float4v*)srin;
    for (int ii = 0; ii < 128; ++ii) {
      float4v wv = w[ii], rv = r4[ii];
      acc += wv[0] * rv[0] + wv[1] * rv[1] + wv[2] * rv[2] + wv[3] * rv[3];
    }
    sh1[jj] = acc / (1.f + __expf(-acc));          // SiLU
  }
  __syncthreads();
  int e = tid >> 6, lane = tid & 63;
  float part = 0.f;
  for (int ii = lane; ii < 512; ii += 64) part += sh1[ii] * rW2[e * 512 + ii];
  red[tid] = part;
  __syncthreads();
  if (tid < 4) {
    float s = rb2[tid];
    for (int k = 0; k < 64; ++k) s += red[tid * 64 + k];
    lg[tid] = s;
  }
  __syncthreads();
  if (tid == 0) {
    float mx = fmaxf(fmaxf(lg[0], lg[1]), fmaxf(lg[2], lg[3]));
    float ex[4], ss = 0.f;
    for (int k = 0; k < 4; ++k) { ex[k] = __expf(lg[k] - mx); ss += ex[k]; }
    float p[4];
    for (int k = 0; k < 4; ++k) { p[k] = ex[k] / ss; probs[b * 4 + k] = p[k]; }
    int i1 = 0;
    for (int k = 1; k < 4; ++k) if (p[k] > p[i1]) i1 = k;
    int i2 = -1;
    for (int k = 0; k < 4; ++k) if (k != i1 && (i2 < 0 || p[k] > p[i2])) i2 = k;
    float den = p[i1] + p[i2];
    for (int k = 0; k < 4; ++k)
      gate[b * 4 + k] = (k == i1) ? p[i1] / den : ((k == i2) ? p[i2] / den : 0.f);
  }
}

__global__ void r3_kernel(const float* __restrict__ probs, float* __restrict__ out_lb) {
  if (threadIdx.x == 0) {
    float u[4] = {0.f, 0.f, 0.f, 0.f};
    for (int b = 0; b < 32; ++b)
      for (int e = 0; e < 4; ++e) u[e] += probs[b * 4 + e];
    float lb = 0.f;
    for (int e = 0; e < 4; ++e) { float dd = u[e] * (1.f / 32.f) - 0.25f; lb += dd * dd; }
    out_lb[0] = 0.01f * (lb * 0.25f);
  }
}

// ---------------- persistent BiLSTM kernel ---------------------------------
// 256 WGs = 8 chains x 32 hidden-slices (16 hid each). One WG/CU guaranteed.
// Wave roles: wn = wave&1 -> which 32 of the 64 gate-rows; wk = wave>>1 ->
// x-GEMM (Wih) or h-GEMM (Whh). Weights live in 128 VGPRs/lane. Partial
// gates recombine through LDS; c-state fp32 in registers; h published bf16
// via global hbuf + per-chain atomic-counter barrier (device scope).

__global__ __launch_bounds__(256, 1) void rnn_kernel(
    const unsigned short* __restrict__ xT,     // [512][32][512]
    const unsigned short* __restrict__ Wp,     // Wih permuted [8][32][64][512]
    const unsigned short* __restrict__ Up,     // Whh permuted
    const float* __restrict__ bias_p,          // [8][32][64]
    unsigned short* __restrict__ hbuf,         // [8][2][32][512]
    unsigned short* __restrict__ hsout,        // [8][512][32][512]
    int* __restrict__ bar) {
  extern __shared__ char smem_raw[];
  unsigned short* stx = (unsigned short*)smem_raw;            // 32 x 520
  unsigned short* sth = stx + 32 * 520;                       // 32 x 520
  float* gsc = (float*)(smem_raw + 2 * 32 * 520 * 2);         // [2][32][64]

  const int tid = threadIdx.x;
  const int wave = tid >> 6, lane = tid & 63;
  const int wg = blockIdx.x;
  const int chain = wg >> 5, sl = wg & 31;
  const int d = chain & 1;
  const int wn = wave & 1, wk = wave >> 1;
  const int col = lane & 31, q2 = lane >> 5;

  // persistent weight fragments: 32 chunks of K=16 (b128 each)
  short8 wb[32];
  {
    const unsigned short* wsrc = (wk == 0 ? Wp : Up)
        + ((size_t)((chain * 32 + sl) * 64 + wn * 32 + col)) * 512 + q2 * 8;
#pragma unroll
    for (int kcc = 0; kcc < 32; ++kcc)
      wb[kcc] = *(const short8*)(wsrc + kcc * 16);
  }

  // pair-phase: thread owns (b_p, jl_p) and (b_p, jl_p+1)
  const int p0 = tid * 2;
  const int b_p = p0 >> 4;
  const int jl_p = p0 & 15;                     // even
  float4v bias4[2];
  bias4[0] = *(const float4v*)(bias_p + (chain * 32 + sl) * 64 + jl_p * 4);
  bias4[1] = *(const float4v*)(bias_p + (chain * 32 + sl) * 64 + (jl_p + 1) * 4);
  float cst[2] = {0.f, 0.f};

  const int barIdx = chain * 32;                // 128B apart

  for (int s = 0; s < 512; ++s) {
    const int tt = d ? (511 - s) : s;
    const int nb = s & 1;
    if (s > 0) {
      if (lane == 0) {
        while (__hip_atomic_load(&bar[barIdx], __ATOMIC_RELAXED, __HIP_MEMORY_SCOPE_AGENT) < 32 * s)
          __builtin_amdgcn_s_sleep(2);
      }
      __syncthreads();
      __threadfence();                          // acquire: see remote h stores
    } else {
      __syncthreads();
    }
    // stage x_tt and h_t into LDS (pad 520 -> conflict-balanced frag reads)
    {
      const unsigned short* xsrc = xT + (size_t)tt * 32 * 512;
      const unsigned short* hsrc = hbuf + (size_t)(chain * 2 + nb) * 32 * 512;
#pragma unroll
      for (int ii = 0; ii < 8; ++ii) {
        int n = tid + ii * 256;
        int r = n >> 6, c8 = n & 63;
        short8 vx = *(const short8*)(xsrc + r * 512 + c8 * 8);
        short8 vh = *(const short8*)(hsrc + r * 512 + c8 * 8);
        *(short8*)(stx + r * 520 + c8 * 8) = vx;
        *(short8*)(sth + r * 520 + c8 * 8) = vh;
      }
    }
    __syncthreads();
    // my K=512 half of the gate GEMM, two interleaved acc chains
    float16v acc0 = {0.f,0.f,0.f,0.f,0.f,0.f,0.f,0.f,0.f,0.f,0.f,0.f,0.f,0.f,0.f,0.f};
    float16v acc1 = acc0;
    {
      const unsigned short* asrc = (wk == 0 ? stx : sth) + col * 520 + q2 * 8;
#pragma unroll
      for (int kcc = 0; kcc < 32; kcc += 2) {
        short8 a0 = *(const short8*)(asrc + kcc * 16);
        short8 a1 = *(const short8*)(asrc + kcc * 16 + 16);
        acc0 = __builtin_amdgcn_mfma_f32_32x32x16_bf16(a0, wb[kcc],     acc0, 0, 0, 0);
        acc1 = __builtin_amdgcn_mfma_f32_32x32x16_bf16(a1, wb[kcc + 1], acc1, 0, 0, 0);
      }
    }
    // publish partial gates: D layout col=lane&31, row=(reg&3)+8*(reg>>2)+4*q2
    {
#pragma unroll
      for (int reg = 0; reg < 16; ++reg) {
        int b = (reg & 3) + 8 * (reg >> 2) + 4 * q2;
        gsc[(wk * 32 + b) * 64 + wn * 32 + col] = acc0[reg] + acc1[reg];
      }
    }
    __syncthreads();
    // LSTM cell update for my two (b, hid) pairs
    unsigned short hb2[2];
#pragma unroll
    for (int j = 0; j < 2; ++j) {
      int jl = jl_p + j;
      float4v ga = *(const float4v*)(gsc + (b_p)*64 + jl * 4);          // x-part
      float4v gb = *(const float4v*)(gsc + (32 + b_p) * 64 + jl * 4);   // h-part
      float4v g = ga + gb + bias4[j];
      float i_ = 1.f / (1.f + __expf(-g[0]));
      float f_ = 1.f / (1.f + __expf(-g[1]));
      float gg = 2.f / (1.f + __expf(-2.f * g[2])) - 1.f;
      float o_ = 1.f / (1.f + __expf(-g[3]));
      float c = f_ * cst[j] + i_ * gg;
      cst[j] = c;
      float h = o_ * (2.f / (1.f + __expf(-2.f * c)) - 1.f);
      hb2[j] = f2bf(h);
    }
    {
      unsigned short* hw = hbuf + (size_t)(chain * 2 + (nb ^ 1)) * 32 * 512;
      unsigned short* ho = hsout + (size_t)(chain * 512 + tt) * 32 * 512;
      int cbase = sl * 16 + jl_p;
      hw[b_p * 512 + cbase]     = hb2[0];
      hw[b_p * 512 + cbase + 1] = hb2[1];
      ho[b_p * 512 + cbase]     = hb2[0];
      ho[b_p * 512 + cbase + 1] = hb2[1];
    }
    __threadfence();                            // release h stores
    __syncthreads();
    if (tid == 0)
      __hip_atomic_fetch_add(&bar[barIdx], 1, __ATOMIC_RELEASE, __HIP_MEMORY_SCOPE_AGENT);
  }
}

// ---------------- gated combine --------------------------------------------
// comb[b][t][dd*512+k] = sum_e gate[b,e] * hs[e*2+dd][t][b][k]   (bf16 out)
__global__ void combine_kernel(const unsigned short* __restrict__ hs,
                               const float* __restrict__ gate,
                               unsigned short* __restrict__ comb) {
  int idx = blockIdx.x * 256 + threadIdx.x;     // 2,097,152 total
  int k8 = idx & 127, t = (idx >> 7) & 511, b = idx >> 16;
  int dd = k8 >> 6, kl = (k8 & 63) * 8;
  float a[8] = {0.f, 0.f, 0.f, 0.f, 0.f, 0.f, 0.f, 0.f};
#pragma unroll
  for (int e = 0; e < 4; ++e) {
    float g = gate[b * 4 + e];
    const unsigned short* src = hs + (size_t)(((e * 2 + dd) * 512 + t) * 32 + b) * 512 + kl;
    short8 v = *(const short8*)src;
#pragma unroll
    for (int r = 0; r < 8; ++r) a[r] += g * bf2f((unsigned short)v[r]);
  }
  short8 o;
#pragma unroll
  for (int r = 0; r < 8; ++r) o[r] = (short)f2bf(a[r]);
  *(short8*)(comb + (size_t)(b * 512 + t) * 1024 + k8 * 8) = o;
}

// ---------------- output projection GEMM -----------------------------------
// C[16384][512] = A(comb bf16 [16384][1024]) * Wout^T + bout, 128x128 tiles
__global__ __launch_bounds__(256) void gemm_out_kernel(
    const unsigned short* __restrict__ A, const unsigned short* __restrict__ Bw,
    const float* __restrict__ bout, float* __restrict__ out) {
  __shared__ unsigned short As[128 * 72];
  __shared__ unsigned short Bs[128 * 72];
  const int tid = threadIdx.x, wave = tid >> 6, lane = tid & 63;
  const int colg = lane & 15, qg = lane >> 4;
  const int m0 = blockIdx.x * 128, n0 = blockIdx.y * 128;
  const int wi = wave >> 1, wj = wave & 1;
  float4v z4 = {0.f, 0.f, 0.f, 0.f};
  float4v acc[4][4];
#pragma unroll
  for (int i = 0; i < 4; ++i)
#pragma unroll
    for (int j = 0; j < 4; ++j) acc[i][j] = z4;

  for (int k0 = 0; k0 < 1024; k0 += 64) {
#pragma unroll
    for (int ii = 0; ii < 4; ++ii) {
      int n = tid + ii * 256;                   // 1024 chunks of 16B
      int r = n >> 3, c8 = n & 7;
      short8 va = *(const short8*)(A  + (size_t)(m0 + r) * 1024 + k0 + c8 * 8);
      short8 vb = *(const short8*)(Bw + (size_t)(n0 + r) * 1024 + k0 + c8 * 8);
      *(short8*)(As + r * 72 + c8 * 8) = va;
      *(short8*)(Bs + r * 72 + c8 * 8) = vb;
    }
    __syncthreads();
#pragma unroll
    for (int kc = 0; kc < 2; ++kc) {
      short8 af[4], bf[4];
#pragma unroll
      for (int i = 0; i < 4; ++i)
        af[i] = *(const short8*)(As + (wi * 64 + i * 16 + colg) * 72 + kc * 32 + qg * 8);
#pragma unroll
      for (int j = 0; j < 4; ++j)
        bf[j] = *(const short8*)(Bs + (wj * 64 + j * 16 + colg) * 72 + kc * 32 + qg * 8);
#pragma unroll
      for (int i = 0; i < 4; ++i)
#pragma unroll
        for (int j = 0; j < 4; ++j)
          acc[i][j] = __builtin_amdgcn_mfma_f32_16x16x32_bf16(af[i], bf[j], acc[i][j], 0, 0, 0);
    }
    __syncthreads();
  }
#pragma unroll
  for (int j = 0; j < 4; ++j) {
    int n = n0 + wj * 64 + j * 16 + colg;
    float bo = bout[n];
#pragma unroll
    for (int i = 0; i < 4; ++i) {
      int mbase = m0 + wi * 64 + i * 16 + qg * 4;
#pragma unroll
      for (int r = 0; r < 4; ++r)
        out[(size_t)(mbase + r) * 512 + n] = acc[i][j][r] + bo;
    }
  }
}

// ---------------- host launcher --------------------------------------------

extern "C" void kernel_launch(void* const* d_in, const int* in_sizes, int n_in,
                              void* d_out, int out_size, void* d_ws, size_t ws_size,
                              hipStream_t stream) {
  (void)in_sizes; (void)n_in; (void)out_size; (void)ws_size;
  const float* x    = (const float*)d_in[0];
  const float* rW1  = (const float*)d_in[1];
  const float* rb1  = (const float*)d_in[2];
  const float* rW2  = (const float*)d_in[3];
  const float* rb2  = (const float*)d_in[4];
  const float* Wih  = (const float*)d_in[5];
  const float* Whh  = (const float*)d_in[6];
  const float* bih  = (const float*)d_in[7];
  const float* bhh  = (const float*)d_in[8];
  const float* Wout = (const float*)d_in[9];
  const float* bout = (const float*)d_in[10];
  float* out = (float*)d_out;

  char* ws = (char*)d_ws;
  size_t off = 0;
  auto alloc = [&](size_t bytes) -> char* {
    char* p = ws + off; off += (bytes + 255) & ~(size_t)255; return p;
  };
  unsigned short* xT     = (unsigned short*)alloc(16777216);   // [512][32][512] bf16
  unsigned short* Wp     = (unsigned short*)alloc(16777216);   // Wih permuted
  unsigned short* Up     = (unsigned short*)alloc(16777216);   // Whh permuted
  unsigned short* Wob    = (unsigned short*)alloc(1048576);    // Wout bf16
  float*          bias_p = (float*)alloc(65536);               // [8][2048]
  unsigned short* hbuf   = (unsigned short*)alloc(524288);     // [8][2][32][512]
  int*            bar    = (int*)alloc(4096);                  // chain barriers
  float*          gate   = (float*)alloc(512);                 // [32][4]
  float*          probs  = (float*)alloc(512);                 // [32][4]
  float*          rin    = (float*)alloc(65536);               // [32][512]
  unsigned short* hs     = (unsigned short*)alloc(134217728);  // [8][512][32][512]
  unsigned short* comb   = (unsigned short*)alloc(33554432);   // [16384][1024]

  // allow >64KB dynamic LDS for the persistent kernel (idempotent, not captured)
  (void)hipFuncSetAttribute((const void*)rnn_kernel,
                            hipFuncAttributeMaxDynamicSharedMemorySize, 82944);

  // zero h0 (both planes) + chain barrier counters (contiguous region)
  hipMemsetAsync(hbuf, 0, 524288 + 4096, stream);

  cx_kernel<<<4096, 256, 0, stream>>>(x, xT);
  cw_kernel<<<4096, 256, 0, stream>>>(Wih, Wp);
  cw_kernel<<<4096, 256, 0, stream>>>(Whh, Up);
  cwout_kernel<<<256, 256, 0, stream>>>(Wout, Wob);
  cbias_kernel<<<64, 256, 0, stream>>>(bih, bhh, bias_p);

  r1_kernel<<<64, 256, 0, stream>>>(x, rin);
  r2_kernel<<<32, 256, 0, stream>>>(rin, rW1, rb1, rW2, rb2, gate, probs);
  r3_kernel<<<1, 64, 0, stream>>>(probs, out + 8388608);

  rnn_kernel<<<256, 256, 82944, stream>>>(xT, Wp, Up, bias_p, hbuf, hs, bar);

  combine_kernel<<<8192, 256, 0, stream>>>(hs, gate, comb);
  gemm_out_kernel<<<dim3(128, 4), 256, 0, stream>>>(comb, Wob, bout, out);
}

// Round 3
// 3499.191 us; speedup vs baseline: 7.1834x; 7.1834x over previous
//
#include <hip/hip_runtime.h>
#include <stdint.h>

// ---------------------------------------------------------------------------
// MoERNN: router -> 4 expert BiLSTMs (fused persistent kernel) -> gated
// combine -> output GEMM.  All heavy math in bf16 MFMA, fp32 accumulate.
// R3 = R2 with the h-staging stride bug fixed (r*128, not r*64):
//   cross-WG h-exchange via write-through LLC atomics + per-WG flag words,
//   no __threadfence (no buffer_inv/buffer_wbl2 cache nukes — R1's killer),
//   x-projection computed before the poll; x_{t+1} prefetched.
// ---------------------------------------------------------------------------

typedef __attribute__((ext_vector_type(8)))  short short8;
typedef __attribute__((ext_vector_type(4)))  float float4v;
typedef __attribute__((ext_vector_type(16))) float float16v;

__device__ __forceinline__ unsigned short f2bf(float x) {
  union { float f; unsigned int u; } v; v.f = x;
  unsigned int r = v.u + 0x7fffu + ((v.u >> 16) & 1u);   // RNE
  return (unsigned short)(r >> 16);
}
__device__ __forceinline__ float bf2f(unsigned short h) {
  union { unsigned int u; float f; } v; v.u = ((unsigned int)h) << 16;
  return v.f;
}

// ---------------- conversion / permutation kernels -------------------------

// x [32][512][512] f32  ->  xT [t][b][i] bf16
__global__ void cx_kernel(const float* __restrict__ x, unsigned short* __restrict__ xT) {
  int idx = blockIdx.x * 256 + threadIdx.x;        // 1,048,576 total
  int i8 = idx & 63, b = (idx >> 6) & 31, t = idx >> 11;
  const float* src = x + ((size_t)(b * 512 + t) * 512 + i8 * 8);
  short8 v;
#pragma unroll
  for (int k = 0; k < 8; ++k) v[k] = (short)f2bf(src[k]);
  *(short8*)(xT + ((size_t)(t * 32 + b) * 512 + i8 * 8)) = v;
}

// W [8][2048][512] f32 -> Wp [chain][slice][n_local = jl*4+g][512] bf16
__global__ void cw_kernel(const float* __restrict__ W, unsigned short* __restrict__ Wp) {
  int idx = blockIdx.x * 256 + threadIdx.x;        // 1,048,576 total
  int k8 = idx & 63, nl = (idx >> 6) & 63, sl = (idx >> 12) & 31, c = idx >> 17;
  int jl = nl >> 2, g = nl & 3;
  int row = g * 512 + sl * 16 + jl;
  const float* src = W + ((size_t)(c * 2048 + row) * 512 + k8 * 8);
  short8 v;
#pragma unroll
  for (int k = 0; k < 8; ++k) v[k] = (short)f2bf(src[k]);
  *(short8*)(Wp + ((size_t)((c * 32 + sl) * 64 + nl) * 512 + k8 * 8)) = v;
}

// Wout [512][1024] f32 -> bf16
__global__ void cwout_kernel(const float* __restrict__ W, unsigned short* __restrict__ Wb) {
  int idx = blockIdx.x * 256 + threadIdx.x;        // 65,536 total
  const float* src = W + (size_t)idx * 8;
  short8 v;
#pragma unroll
  for (int k = 0; k < 8; ++k) v[k] = (short)f2bf(src[k]);
  *(short8*)(Wb + (size_t)idx * 8) = v;
}

// bias_p[(c*32+sl)*64 + nl] = bih + bhh (permuted like Wp rows)
__global__ void cbias_kernel(const float* __restrict__ bih, const float* __restrict__ bhh,
                             float* __restrict__ bias_p) {
  int idx = blockIdx.x * 256 + threadIdx.x;        // 16,384 total
  int nl = idx & 63, sl = (idx >> 6) & 31, c = idx >> 11;
  int jl = nl >> 2, g = nl & 3;
  int row = g * 512 + sl * 16 + jl;
  bias_p[idx] = bih[c * 2048 + row] + bhh[c * 2048 + row];
}

// ---------------- router ----------------------------------------------------

__global__ void r1_kernel(const float* __restrict__ x, float* __restrict__ rin) {
  int b = blockIdx.x >> 1, half = blockIdx.x & 1;
  int i = half * 256 + threadIdx.x;
  float s = 0.f;
  for (int t = 0; t < 512; ++t) s += x[(size_t)(b * 512 + t) * 512 + i];
  rin[b * 512 + i] = s * (1.f / 512.f);
}

__global__ __launch_bounds__(256) void r2_kernel(
    const float* __restrict__ rin, const float* __restrict__ rW1, const float* __restrict__ rb1,
    const float* __restrict__ rW2, const float* __restrict__ rb2,
    float* __restrict__ gate, float* __restrict__ probs) {
  __shared__ float srin[512];
  __shared__ float sh1[512];
  __shared__ float red[256];
  __shared__ float lg[4];
  int b = blockIdx.x, tid = threadIdx.x;
  srin[tid] = rin[b * 512 + tid];
  srin[tid + 256] = rin[b * 512 + tid + 256];
  __syncthreads();
  for (int rep = 0; rep < 2; ++rep) {
    int jj = tid + rep * 256;
    float acc = rb1[jj];
    const float4v* w  = (const float4v*)(rW1 + (size_t)jj * 512);
    const float4v* r4 = (const float4v*)srin;
    for (int ii = 0; ii < 128; ++ii) {
      float4v wv = w[ii], rv = r4[ii];
      acc += wv[0] * rv[0] + wv[1] * rv[1] + wv[2] * rv[2] + wv[3] * rv[3];
    }
    sh1[jj] = acc / (1.f + __expf(-acc));          // SiLU
  }
  __syncthreads();
  int e = tid >> 6, lane = tid & 63;
  float part = 0.f;
  for (int ii = lane; ii < 512; ii += 64) part += sh1[ii] * rW2[e * 512 + ii];
  red[tid] = part;
  __syncthreads();
  if (tid < 4) {
    float s = rb2[tid];
    for (int k = 0; k < 64; ++k) s += red[tid * 64 + k];
    lg[tid] = s;
  }
  __syncthreads();
  if (tid == 0) {
    float mx = fmaxf(fmaxf(lg[0], lg[1]), fmaxf(lg[2], lg[3]));
    float ex[4], ss = 0.f;
    for (int k = 0; k < 4; ++k) { ex[k] = __expf(lg[k] - mx); ss += ex[k]; }
    float p[4];
    for (int k = 0; k < 4; ++k) { p[k] = ex[k] / ss; probs[b * 4 + k] = p[k]; }
    int i1 = 0;
    for (int k = 1; k < 4; ++k) if (p[k] > p[i1]) i1 = k;
    int i2 = -1;
    for (int k = 0; k < 4; ++k) if (k != i1 && (i2 < 0 || p[k] > p[i2])) i2 = k;
    float den = p[i1] + p[i2];
    for (int k = 0; k < 4; ++k)
      gate[b * 4 + k] = (k == i1) ? p[i1] / den : ((k == i2) ? p[i2] / den : 0.f);
  }
}

__global__ void r3_kernel(const float* __restrict__ probs, float* __restrict__ out_lb) {
  if (threadIdx.x == 0) {
    float u[4] = {0.f, 0.f, 0.f, 0.f};
    for (int b = 0; b < 32; ++b)
      for (int e = 0; e < 4; ++e) u[e] += probs[b * 4 + e];
    float lb = 0.f;
    for (int e = 0; e < 4; ++e) { float dd = u[e] * (1.f / 32.f) - 0.25f; lb += dd * dd; }
    out_lb[0] = 0.01f * (lb * 0.25f);
  }
}

// ---------------- persistent BiLSTM kernel ---------------------------------
// 256 WGs = 8 chains x 32 hidden-slices (16 hid each). One WG/CU (LDS-bound),
// grid == CU count -> co-resident, spin-safe.
// Each wave holds a (N-half wn) x (K-half wk) slice of BOTH Wih and Whh in
// 128 VGPRs.  Per step: gx from LDS x (before poll) -> poll per-WG flag
// words (relaxed agent atomics, LLC) -> stage h_{t-1} from hsout via relaxed
// agent 8B atomic loads -> gh accumulated onto gx -> gsc combine -> cell ->
// h stored with relaxed agent 4B atomic stores (write-through; no fences).

__global__ __launch_bounds__(256, 1) void rnn_kernel(
    const unsigned short* __restrict__ xT,     // [512][32][512]
    const unsigned short* __restrict__ Wp,     // Wih permuted [8][32][64][512]
    const unsigned short* __restrict__ Up,     // Whh permuted
    const float* __restrict__ bias_p,          // [8][32][64]
    unsigned short* __restrict__ hsout,        // [8][512][32][512]
    unsigned int* __restrict__ bar) {          // [8][32] per-WG flag words
  extern __shared__ char smem_raw[];
  unsigned short* stx = (unsigned short*)smem_raw;            // 2 x 32 x 520
  unsigned short* sth = stx + 2 * 16640;                      // 32 x 520
  float* gsc = (float*)(smem_raw + 3 * 16640 * 2);            // [2][32][64]

  const int tid = threadIdx.x;
  const int wave = tid >> 6, lane = tid & 63;
  const int wg = blockIdx.x;
  const int chain = wg >> 5, sl = wg & 31;
  const int d = chain & 1;
  const int wn = wave & 1, wk = wave >> 1;
  const int col = lane & 31, q2 = lane >> 5;

  // persistent weight fragments: (N-half, K-half) of both matrices
  short8 wbx[16], wbh[16];
  {
    const size_t rowoff = ((size_t)((chain * 32 + sl) * 64 + wn * 32 + col)) * 512
                        + wk * 256 + q2 * 8;
    const unsigned short* wsx = Wp + rowoff;
    const unsigned short* wsh = Up + rowoff;
#pragma unroll
    for (int kcc = 0; kcc < 16; ++kcc) {
      wbx[kcc] = *(const short8*)(wsx + kcc * 16);
      wbh[kcc] = *(const short8*)(wsh + kcc * 16);
    }
  }

  // cell-phase ownership: thread owns (b_p, jl_p) and (b_p, jl_p+1)
  const int p0 = tid * 2;
  const int b_p = p0 >> 4;
  const int jl_p = p0 & 15;                     // even
  float4v bias4[2];
  bias4[0] = *(const float4v*)(bias_p + (chain * 32 + sl) * 64 + jl_p * 4);
  bias4[1] = *(const float4v*)(bias_p + (chain * 32 + sl) * 64 + (jl_p + 1) * 4);
  float cst[2] = {0.f, 0.f};

  // stage x for step 0
  {
    const int tt0 = d ? 511 : 0;
    const unsigned short* xsrc = xT + (size_t)tt0 * 16384;
#pragma unroll
    for (int ii = 0; ii < 8; ++ii) {
      int n = tid + ii * 256;
      int r = n >> 6, c8 = n & 63;
      short8 v = *(const short8*)(xsrc + r * 512 + c8 * 8);
      *(short8*)(stx + r * 520 + c8 * 8) = v;
    }
  }
  __syncthreads();

  for (int s = 0; s < 512; ++s) {
    const int tt = d ? (511 - s) : s;
    const int cur = s & 1;
    const unsigned short* stxc = stx + cur * 16640;

    // ---- x-part of gates (no dependency on other WGs) ----
    float16v acc0 = {0.f,0.f,0.f,0.f,0.f,0.f,0.f,0.f,0.f,0.f,0.f,0.f,0.f,0.f,0.f,0.f};
    float16v acc1 = acc0;
    {
      const unsigned short* asrc = stxc + col * 520 + wk * 256 + q2 * 8;
#pragma unroll
      for (int kcc = 0; kcc < 16; kcc += 2) {
        short8 a0 = *(const short8*)(asrc + kcc * 16);
        short8 a1 = *(const short8*)(asrc + kcc * 16 + 16);
        acc0 = __builtin_amdgcn_mfma_f32_32x32x16_bf16(a0, wbx[kcc],     acc0, 0, 0, 0);
        acc1 = __builtin_amdgcn_mfma_f32_32x32x16_bf16(a1, wbx[kcc + 1], acc1, 0, 0, 0);
      }
    }

    // ---- issue x prefetch for step s+1 (drains during poll/h phase) ----
    short8 xpre[8];
    if (s < 511) {
      const int ttn = d ? (510 - s) : (s + 1);
      const unsigned short* xsrc = xT + (size_t)ttn * 16384;
#pragma unroll
      for (int ii = 0; ii < 8; ++ii) {
        int n = tid + ii * 256;
        int r = n >> 6, c8 = n & 63;
        xpre[ii] = *(const short8*)(xsrc + r * 512 + c8 * 8);
      }
    }

    if (s > 0) {
      // ---- poll: all 32 producer flags of my chain must reach s ----
      {
        const int fi = lane & 31;
        const unsigned int* fp = bar + chain * 32 + fi;
        for (;;) {
          unsigned int v = __hip_atomic_load(fp, __ATOMIC_RELAXED, __HIP_MEMORY_SCOPE_AGENT);
          if (__ballot(v >= (unsigned int)s) == ~0ull) break;
          __builtin_amdgcn_s_sleep(1);
        }
        asm volatile("" ::: "memory");
      }
      // ---- stage h_{t_prev} from LLC into LDS ----
      {
        const int ttp = d ? (512 - s) : (s - 1);
        const unsigned long long* hsrc =
            (const unsigned long long*)(hsout + ((size_t)(chain * 512 + ttp) * 32) * 512);
#pragma unroll
        for (int ii = 0; ii < 16; ++ii) {
          int n = tid + ii * 256;                 // 4096 8B chunks
          int r = n >> 7, c4 = n & 127;           // row = 512 shorts = 128 chunks
          unsigned long long v =
              __hip_atomic_load(hsrc + r * 128 + c4, __ATOMIC_RELAXED, __HIP_MEMORY_SCOPE_AGENT);
          *(unsigned long long*)(sth + r * 520 + c4 * 4) = v;
        }
      }
      __syncthreads();
      // ---- h-part of gates, accumulate onto x-part ----
      {
        const unsigned short* asrc = sth + col * 520 + wk * 256 + q2 * 8;
#pragma unroll
        for (int kcc = 0; kcc < 16; kcc += 2) {
          short8 a0 = *(const short8*)(asrc + kcc * 16);
          short8 a1 = *(const short8*)(asrc + kcc * 16 + 16);
          acc0 = __builtin_amdgcn_mfma_f32_32x32x16_bf16(a0, wbh[kcc],     acc0, 0, 0, 0);
          acc1 = __builtin_amdgcn_mfma_f32_32x32x16_bf16(a1, wbh[kcc + 1], acc1, 0, 0, 0);
        }
      }
    }

    // ---- publish partial gates (D layout: col=lane&31, row=(reg&3)+8*(reg>>2)+4*q2)
#pragma unroll
    for (int reg = 0; reg < 16; ++reg) {
      int b = (reg & 3) + 8 * (reg >> 2) + 4 * q2;
      gsc[(wk * 32 + b) * 64 + wn * 32 + col] = acc0[reg] + acc1[reg];
    }
    __syncthreads();

    // ---- LSTM cell update for my two (b, hid) pairs ----
    unsigned short hb2[2];
#pragma unroll
    for (int j = 0; j < 2; ++j) {
      int jl = jl_p + j;
      float4v ga = *(const float4v*)(gsc + b_p * 64 + jl * 4);          // K-half 0
      float4v gb = *(const float4v*)(gsc + (32 + b_p) * 64 + jl * 4);   // K-half 1
      float4v g = ga + gb + bias4[j];
      float i_ = 1.f / (1.f + __expf(-g[0]));
      float f_ = 1.f / (1.f + __expf(-g[1]));
      float gg = 2.f / (1.f + __expf(-2.f * g[2])) - 1.f;
      float o_ = 1.f / (1.f + __expf(-g[3]));
      float c = f_ * cst[j] + i_ * gg;
      cst[j] = c;
      float h = o_ * (2.f / (1.f + __expf(-2.f * c)) - 1.f);
      hb2[j] = f2bf(h);
    }
    {
      // write-through h store (2 bf16 packed in one dword, LLC-coherent)
      unsigned int hv = (unsigned int)hb2[0] | ((unsigned int)hb2[1] << 16);
      unsigned int* hdst = (unsigned int*)(hsout
          + ((size_t)(chain * 512 + tt) * 32 + b_p) * 512 + sl * 16 + jl_p);
      __hip_atomic_store(hdst, hv, __ATOMIC_RELAXED, __HIP_MEMORY_SCOPE_AGENT);
    }

    // drain h store (and x prefetch) before signaling
    asm volatile("s_waitcnt vmcnt(0)" ::: "memory");

    // ---- write prefetched x into the other LDS buffer ----
    if (s < 511) {
      unsigned short* stxn = stx + (cur ^ 1) * 16640;
#pragma unroll
      for (int ii = 0; ii < 8; ++ii) {
        int n = tid + ii * 256;
        int r = n >> 6, c8 = n & 63;
        *(short8*)(stxn + r * 520 + c8 * 8) = xpre[ii];
      }
    }
    __syncthreads();
    if (tid == 0)
      __hip_atomic_store(bar + chain * 32 + sl, (unsigned int)(s + 1),
                         __ATOMIC_RELAXED, __HIP_MEMORY_SCOPE_AGENT);
  }
}

// ---------------- gated combine --------------------------------------------
// comb[b][t][dd*512+k] = sum_e gate[b,e] * hs[e*2+dd][t][b][k]   (bf16 out)
__global__ void combine_kernel(const unsigned short* __restrict__ hs,
                               const float* __restrict__ gate,
                               unsigned short* __restrict__ comb) {
  int idx = blockIdx.x * 256 + threadIdx.x;     // 2,097,152 total
  int k8 = idx & 127, t = (idx >> 7) & 511, b = idx >> 16;
  int dd = k8 >> 6, kl = (k8 & 63) * 8;
  float a[8] = {0.f, 0.f, 0.f, 0.f, 0.f, 0.f, 0.f, 0.f};
#pragma unroll
  for (int e = 0; e < 4; ++e) {
    float g = gate[b * 4 + e];
    const unsigned short* src = hs + (size_t)(((e * 2 + dd) * 512 + t) * 32 + b) * 512 + kl;
    short8 v = *(const short8*)src;
#pragma unroll
    for (int r = 0; r < 8; ++r) a[r] += g * bf2f((unsigned short)v[r]);
  }
  short8 o;
#pragma unroll
  for (int r = 0; r < 8; ++r) o[r] = (short)f2bf(a[r]);
  *(short8*)(comb + (size_t)(b * 512 + t) * 1024 + k8 * 8) = o;
}

// ---------------- output projection GEMM -----------------------------------
// C[16384][512] = A(comb bf16 [16384][1024]) * Wout^T + bout, 128x128 tiles
__global__ __launch_bounds__(256) void gemm_out_kernel(
    const unsigned short* __restrict__ A, const unsigned short* __restrict__ Bw,
    const float* __restrict__ bout, float* __restrict__ out) {
  __shared__ unsigned short As[128 * 72];
  __shared__ unsigned short Bs[128 * 72];
  const int tid = threadIdx.x, wave = tid >> 6, lane = tid & 63;
  const int colg = lane & 15, qg = lane >> 4;
  const int m0 = blockIdx.x * 128, n0 = blockIdx.y * 128;
  const int wi = wave >> 1, wj = wave & 1;
  float4v z4 = {0.f, 0.f, 0.f, 0.f};
  float4v acc[4][4];
#pragma unroll
  for (int i = 0; i < 4; ++i)
#pragma unroll
    for (int j = 0; j < 4; ++j) acc[i][j] = z4;

  for (int k0 = 0; k0 < 1024; k0 += 64) {
#pragma unroll
    for (int ii = 0; ii < 4; ++ii) {
      int n = tid + ii * 256;                   // 1024 chunks of 16B
      int r = n >> 3, c8 = n & 7;
      short8 va = *(const short8*)(A  + (size_t)(m0 + r) * 1024 + k0 + c8 * 8);
      short8 vb = *(const short8*)(Bw + (size_t)(n0 + r) * 1024 + k0 + c8 * 8);
      *(short8*)(As + r * 72 + c8 * 8) = va;
      *(short8*)(Bs + r * 72 + c8 * 8) = vb;
    }
    __syncthreads();
#pragma unroll
    for (int kc = 0; kc < 2; ++kc) {
      short8 af[4], bf[4];
#pragma unroll
      for (int i = 0; i < 4; ++i)
        af[i] = *(const short8*)(As + (wi * 64 + i * 16 + colg) * 72 + kc * 32 + qg * 8);
#pragma unroll
      for (int j = 0; j < 4; ++j)
        bf[j] = *(const short8*)(Bs + (wj * 64 + j * 16 + colg) * 72 + kc * 32 + qg * 8);
#pragma unroll
      for (int i = 0; i < 4; ++i)
#pragma unroll
        for (int j = 0; j < 4; ++j)
          acc[i][j] = __builtin_amdgcn_mfma_f32_16x16x32_bf16(af[i], bf[j], acc[i][j], 0, 0, 0);
    }
    __syncthreads();
  }
#pragma unroll
  for (int j = 0; j < 4; ++j) {
    int n = n0 + wj * 64 + j * 16 + colg;
    float bo = bout[n];
#pragma unroll
    for (int i = 0; i < 4; ++i) {
      int mbase = m0 + wi * 64 + i * 16 + qg * 4;
#pragma unroll
      for (int r = 0; r < 4; ++r)
        out[(size_t)(mbase + r) * 512 + n] = acc[i][j][r] + bo;
    }
  }
}

// ---------------- host launcher --------------------------------------------

extern "C" void kernel_launch(void* const* d_in, const int* in_sizes, int n_in,
                              void* d_out, int out_size, void* d_ws, size_t ws_size,
                              hipStream_t stream) {
  (void)in_sizes; (void)n_in; (void)out_size; (void)ws_size;
  const float* x    = (const float*)d_in[0];
  const float* rW1  = (const float*)d_in[1];
  const float* rb1  = (const float*)d_in[2];
  const float* rW2  = (const float*)d_in[3];
  const float* rb2  = (const float*)d_in[4];
  const float* Wih  = (const float*)d_in[5];
  const float* Whh  = (const float*)d_in[6];
  const float* bih  = (const float*)d_in[7];
  const float* bhh  = (const float*)d_in[8];
  const float* Wout = (const float*)d_in[9];
  const float* bout = (const float*)d_in[10];
  float* out = (float*)d_out;

  char* ws = (char*)d_ws;
  size_t off = 0;
  auto alloc = [&](size_t bytes) -> char* {
    char* p = ws + off; off += (bytes + 255) & ~(size_t)255; return p;
  };
  unsigned short* xT     = (unsigned short*)alloc(16777216);   // [512][32][512] bf16
  unsigned short* Wp     = (unsigned short*)alloc(16777216);   // Wih permuted
  unsigned short* Up     = (unsigned short*)alloc(16777216);   // Whh permuted
  unsigned short* Wob    = (unsigned short*)alloc(1048576);    // Wout bf16
  float*          bias_p = (float*)alloc(65536);               // [8][2048]
  unsigned int*   bar    = (unsigned int*)alloc(4096);         // per-WG flags
  float*          gate   = (float*)alloc(512);                 // [32][4]
  float*          probs  = (float*)alloc(512);                 // [32][4]
  float*          rin    = (float*)alloc(65536);               // [32][512]
  unsigned short* hs     = (unsigned short*)alloc(134217728);  // [8][512][32][512]
  unsigned short* comb   = (unsigned short*)alloc(33554432);   // [16384][1024]

  // allow >64KB dynamic LDS for the persistent kernel
  (void)hipFuncSetAttribute((const void*)rnn_kernel,
                            hipFuncAttributeMaxDynamicSharedMemorySize, 116224);

  // zero the per-WG flag words
  hipMemsetAsync(bar, 0, 4096, stream);

  cx_kernel<<<4096, 256, 0, stream>>>(x, xT);
  cw_kernel<<<4096, 256, 0, stream>>>(Wih, Wp);
  cw_kernel<<<4096, 256, 0, stream>>>(Whh, Up);
  cwout_kernel<<<256, 256, 0, stream>>>(Wout, Wob);
  cbias_kernel<<<64, 256, 0, stream>>>(bih, bhh, bias_p);

  r1_kernel<<<64, 256, 0, stream>>>(x, rin);
  r2_kernel<<<32, 256, 0, stream>>>(rin, rW1, rb1, rW2, rb2, gate, probs);
  r3_kernel<<<1, 64, 0, stream>>>(probs, out + 8388608);

  rnn_kernel<<<256, 256, 116224, stream>>>(xT, Wp, Up, bias_p, hs, bar);

  combine_kernel<<<8192, 256, 0, stream>>>(hs, gate, comb);
  gemm_out_kernel<<<dim3(128, 4), 256, 0, stream>>>(comb, Wob, bout, out);
}

// Round 4
// 3423.256 us; speedup vs baseline: 7.3427x; 1.0222x over previous
//
#include <hip/hip_runtime.h>
#include <stdint.h>

// ---------------------------------------------------------------------------
// MoERNN: router -> 4 expert BiLSTMs (fused persistent kernel) -> gated
// combine -> output GEMM.  All heavy math in bf16 MFMA, fp32 accumulate.
// R4 = R3 + poll-storm fixes:
//   - only wave 0 polls the chain flags (was: all 4 waves spinning)
//   - per-WG flag words padded to 128B lines (was: 32 flags in 2 lines)
//   - producer tail reordered: h store -> xpre->LDS -> vmcnt(0) -> barrier ->
//     flag store (flag publishes ~200cyc earlier; LDS write hides in drain)
// ---------------------------------------------------------------------------

typedef __attribute__((ext_vector_type(8)))  short short8;
typedef __attribute__((ext_vector_type(4)))  float float4v;
typedef __attribute__((ext_vector_type(16))) float float16v;

__device__ __forceinline__ unsigned short f2bf(float x) {
  union { float f; unsigned int u; } v; v.f = x;
  unsigned int r = v.u + 0x7fffu + ((v.u >> 16) & 1u);   // RNE
  return (unsigned short)(r >> 16);
}
__device__ __forceinline__ float bf2f(unsigned short h) {
  union { unsigned int u; float f; } v; v.u = ((unsigned int)h) << 16;
  return v.f;
}

// ---------------- conversion / permutation kernels -------------------------

// x [32][512][512] f32  ->  xT [t][b][i] bf16
__global__ void cx_kernel(const float* __restrict__ x, unsigned short* __restrict__ xT) {
  int idx = blockIdx.x * 256 + threadIdx.x;        // 1,048,576 total
  int i8 = idx & 63, b = (idx >> 6) & 31, t = idx >> 11;
  const float* src = x + ((size_t)(b * 512 + t) * 512 + i8 * 8);
  short8 v;
#pragma unroll
  for (int k = 0; k < 8; ++k) v[k] = (short)f2bf(src[k]);
  *(short8*)(xT + ((size_t)(t * 32 + b) * 512 + i8 * 8)) = v;
}

// W [8][2048][512] f32 -> Wp [chain][slice][n_local = jl*4+g][512] bf16
__global__ void cw_kernel(const float* __restrict__ W, unsigned short* __restrict__ Wp) {
  int idx = blockIdx.x * 256 + threadIdx.x;        // 1,048,576 total
  int k8 = idx & 63, nl = (idx >> 6) & 63, sl = (idx >> 12) & 31, c = idx >> 17;
  int jl = nl >> 2, g = nl & 3;
  int row = g * 512 + sl * 16 + jl;
  const float* src = W + ((size_t)(c * 2048 + row) * 512 + k8 * 8);
  short8 v;
#pragma unroll
  for (int k = 0; k < 8; ++k) v[k] = (short)f2bf(src[k]);
  *(short8*)(Wp + ((size_t)((c * 32 + sl) * 64 + nl) * 512 + k8 * 8)) = v;
}

// Wout [512][1024] f32 -> bf16
__global__ void cwout_kernel(const float* __restrict__ W, unsigned short* __restrict__ Wb) {
  int idx = blockIdx.x * 256 + threadIdx.x;        // 65,536 total
  const float* src = W + (size_t)idx * 8;
  short8 v;
#pragma unroll
  for (int k = 0; k < 8; ++k) v[k] = (short)f2bf(src[k]);
  *(short8*)(Wb + (size_t)idx * 8) = v;
}

// bias_p[(c*32+sl)*64 + nl] = bih + bhh (permuted like Wp rows)
__global__ void cbias_kernel(const float* __restrict__ bih, const float* __restrict__ bhh,
                             float* __restrict__ bias_p) {
  int idx = blockIdx.x * 256 + threadIdx.x;        // 16,384 total
  int nl = idx & 63, sl = (idx >> 6) & 31, c = idx >> 11;
  int jl = nl >> 2, g = nl & 3;
  int row = g * 512 + sl * 16 + jl;
  bias_p[idx] = bih[c * 2048 + row] + bhh[c * 2048 + row];
}

// ---------------- router ----------------------------------------------------

__global__ void r1_kernel(const float* __restrict__ x, float* __restrict__ rin) {
  int b = blockIdx.x >> 1, half = blockIdx.x & 1;
  int i = half * 256 + threadIdx.x;
  float s = 0.f;
  for (int t = 0; t < 512; ++t) s += x[(size_t)(b * 512 + t) * 512 + i];
  rin[b * 512 + i] = s * (1.f / 512.f);
}

__global__ __launch_bounds__(256) void r2_kernel(
    const float* __restrict__ rin, const float* __restrict__ rW1, const float* __restrict__ rb1,
    const float* __restrict__ rW2, const float* __restrict__ rb2,
    float* __restrict__ gate, float* __restrict__ probs) {
  __shared__ float srin[512];
  __shared__ float sh1[512];
  __shared__ float red[256];
  __shared__ float lg[4];
  int b = blockIdx.x, tid = threadIdx.x;
  srin[tid] = rin[b * 512 + tid];
  srin[tid + 256] = rin[b * 512 + tid + 256];
  __syncthreads();
  for (int rep = 0; rep < 2; ++rep) {
    int jj = tid + rep * 256;
    float acc = rb1[jj];
    const float4v* w  = (const float4v*)(rW1 + (size_t)jj * 512);
    const float4v* r4 = (const float4v*)srin;
    for (int ii = 0; ii < 128; ++ii) {
      float4v wv = w[ii], rv = r4[ii];
      acc += wv[0] * rv[0] + wv[1] * rv[1] + wv[2] * rv[2] + wv[3] * rv[3];
    }
    sh1[jj] = acc / (1.f + __expf(-acc));          // SiLU
  }
  __syncthreads();
  int e = tid >> 6, lane = tid & 63;
  float part = 0.f;
  for (int ii = lane; ii < 512; ii += 64) part += sh1[ii] * rW2[e * 512 + ii];
  red[tid] = part;
  __syncthreads();
  if (tid < 4) {
    float s = rb2[tid];
    for (int k = 0; k < 64; ++k) s += red[tid * 64 + k];
    lg[tid] = s;
  }
  __syncthreads();
  if (tid == 0) {
    float mx = fmaxf(fmaxf(lg[0], lg[1]), fmaxf(lg[2], lg[3]));
    float ex[4], ss = 0.f;
    for (int k = 0; k < 4; ++k) { ex[k] = __expf(lg[k] - mx); ss += ex[k]; }
    float p[4];
    for (int k = 0; k < 4; ++k) { p[k] = ex[k] / ss; probs[b * 4 + k] = p[k]; }
    int i1 = 0;
    for (int k = 1; k < 4; ++k) if (p[k] > p[i1]) i1 = k;
    int i2 = -1;
    for (int k = 0; k < 4; ++k) if (k != i1 && (i2 < 0 || p[k] > p[i2])) i2 = k;
    float den = p[i1] + p[i2];
    for (int k = 0; k < 4; ++k)
      gate[b * 4 + k] = (k == i1) ? p[i1] / den : ((k == i2) ? p[i2] / den : 0.f);
  }
}

__global__ void r3_kernel(const float* __restrict__ probs, float* __restrict__ out_lb) {
  if (threadIdx.x == 0) {
    float u[4] = {0.f, 0.f, 0.f, 0.f};
    for (int b = 0; b < 32; ++b)
      for (int e = 0; e < 4; ++e) u[e] += probs[b * 4 + e];
    float lb = 0.f;
    for (int e = 0; e < 4; ++e) { float dd = u[e] * (1.f / 32.f) - 0.25f; lb += dd * dd; }
    out_lb[0] = 0.01f * (lb * 0.25f);
  }
}

// ---------------- persistent BiLSTM kernel ---------------------------------
// 256 WGs = 8 chains x 32 hidden-slices (16 hid each). One WG/CU (LDS-bound),
// grid == CU count -> co-resident, spin-safe.
// Each wave holds a (N-half wn) x (K-half wk) slice of BOTH Wih and Whh in
// 128 VGPRs.  Per step: gx from LDS x (before poll) -> wave0 polls padded
// per-WG flag lines (relaxed agent atomics, LLC) -> stage h_{t-1} from hsout
// via relaxed agent 8B atomic loads -> gh accumulated onto gx -> gsc combine
// -> cell -> h stored with relaxed agent 4B atomic stores (no fences).

__global__ __launch_bounds__(256, 1) void rnn_kernel(
    const unsigned short* __restrict__ xT,     // [512][32][512]
    const unsigned short* __restrict__ Wp,     // Wih permuted [8][32][64][512]
    const unsigned short* __restrict__ Up,     // Whh permuted
    const float* __restrict__ bias_p,          // [8][32][64]
    unsigned short* __restrict__ hsout,        // [8][512][32][512]
    unsigned int* __restrict__ bar) {          // [8][32] flags, 128B stride
  extern __shared__ char smem_raw[];
  unsigned short* stx = (unsigned short*)smem_raw;            // 2 x 32 x 520
  unsigned short* sth = stx + 2 * 16640;                      // 32 x 520
  float* gsc = (float*)(smem_raw + 3 * 16640 * 2);            // [2][32][64]

  const int tid = threadIdx.x;
  const int wave = tid >> 6, lane = tid & 63;
  const int wg = blockIdx.x;
  const int chain = wg >> 5, sl = wg & 31;
  const int d = chain & 1;
  const int wn = wave & 1, wk = wave >> 1;
  const int col = lane & 31, q2 = lane >> 5;

  // persistent weight fragments: (N-half, K-half) of both matrices
  short8 wbx[16], wbh[16];
  {
    const size_t rowoff = ((size_t)((chain * 32 + sl) * 64 + wn * 32 + col)) * 512
                        + wk * 256 + q2 * 8;
    const unsigned short* wsx = Wp + rowoff;
    const unsigned short* wsh = Up + rowoff;
#pragma unroll
    for (int kcc = 0; kcc < 16; ++kcc) {
      wbx[kcc] = *(const short8*)(wsx + kcc * 16);
      wbh[kcc] = *(const short8*)(wsh + kcc * 16);
    }
  }

  // cell-phase ownership: thread owns (b_p, jl_p) and (b_p, jl_p+1)
  const int p0 = tid * 2;
  const int b_p = p0 >> 4;
  const int jl_p = p0 & 15;                     // even
  float4v bias4[2];
  bias4[0] = *(const float4v*)(bias_p + (chain * 32 + sl) * 64 + jl_p * 4);
  bias4[1] = *(const float4v*)(bias_p + (chain * 32 + sl) * 64 + (jl_p + 1) * 4);
  float cst[2] = {0.f, 0.f};

  // stage x for step 0
  {
    const int tt0 = d ? 511 : 0;
    const unsigned short* xsrc = xT + (size_t)tt0 * 16384;
#pragma unroll
    for (int ii = 0; ii < 8; ++ii) {
      int n = tid + ii * 256;
      int r = n >> 6, c8 = n & 63;
      short8 v = *(const short8*)(xsrc + r * 512 + c8 * 8);
      *(short8*)(stx + r * 520 + c8 * 8) = v;
    }
  }
  __syncthreads();

  for (int s = 0; s < 512; ++s) {
    const int tt = d ? (511 - s) : s;
    const int cur = s & 1;
    const unsigned short* stxc = stx + cur * 16640;

    // ---- x-part of gates (no dependency on other WGs) ----
    float16v acc0 = {0.f,0.f,0.f,0.f,0.f,0.f,0.f,0.f,0.f,0.f,0.f,0.f,0.f,0.f,0.f,0.f};
    float16v acc1 = acc0;
    {
      const unsigned short* asrc = stxc + col * 520 + wk * 256 + q2 * 8;
#pragma unroll
      for (int kcc = 0; kcc < 16; kcc += 2) {
        short8 a0 = *(const short8*)(asrc + kcc * 16);
        short8 a1 = *(const short8*)(asrc + kcc * 16 + 16);
        acc0 = __builtin_amdgcn_mfma_f32_32x32x16_bf16(a0, wbx[kcc],     acc0, 0, 0, 0);
        acc1 = __builtin_amdgcn_mfma_f32_32x32x16_bf16(a1, wbx[kcc + 1], acc1, 0, 0, 0);
      }
    }

    // ---- issue x prefetch for step s+1 (drains during poll/h phase) ----
    short8 xpre[8];
    if (s < 511) {
      const int ttn = d ? (510 - s) : (s + 1);
      const unsigned short* xsrc = xT + (size_t)ttn * 16384;
#pragma unroll
      for (int ii = 0; ii < 8; ++ii) {
        int n = tid + ii * 256;
        int r = n >> 6, c8 = n & 63;
        xpre[ii] = *(const short8*)(xsrc + r * 512 + c8 * 8);
      }
    }

    if (s > 0) {
      // ---- poll (wave 0 only): all 32 producer flags must reach s ----
      if (wave == 0) {
        const unsigned int* fp = bar + (size_t)(chain * 32 + (lane & 31)) * 32;
        for (;;) {
          unsigned int v = __hip_atomic_load(fp, __ATOMIC_RELAXED, __HIP_MEMORY_SCOPE_AGENT);
          if (__ballot(v >= (unsigned int)s) == ~0ull) break;
          __builtin_amdgcn_s_sleep(1);
        }
      }
      __syncthreads();                           // release waves 1..3
      // ---- stage h_{t_prev} from LLC into LDS ----
      {
        const int ttp = d ? (512 - s) : (s - 1);
        const unsigned long long* hsrc =
            (const unsigned long long*)(hsout + ((size_t)(chain * 512 + ttp) * 32) * 512);
#pragma unroll
        for (int ii = 0; ii < 16; ++ii) {
          int n = tid + ii * 256;                 // 4096 8B chunks
          int r = n >> 7, c4 = n & 127;           // row = 512 shorts = 128 chunks
          unsigned long long v =
              __hip_atomic_load(hsrc + r * 128 + c4, __ATOMIC_RELAXED, __HIP_MEMORY_SCOPE_AGENT);
          *(unsigned long long*)(sth + r * 520 + c4 * 4) = v;
        }
      }
      __syncthreads();
      // ---- h-part of gates, accumulate onto x-part ----
      {
        const unsigned short* asrc = sth + col * 520 + wk * 256 + q2 * 8;
#pragma unroll
        for (int kcc = 0; kcc < 16; kcc += 2) {
          short8 a0 = *(const short8*)(asrc + kcc * 16);
          short8 a1 = *(const short8*)(asrc + kcc * 16 + 16);
          acc0 = __builtin_amdgcn_mfma_f32_32x32x16_bf16(a0, wbh[kcc],     acc0, 0, 0, 0);
          acc1 = __builtin_amdgcn_mfma_f32_32x32x16_bf16(a1, wbh[kcc + 1], acc1, 0, 0, 0);
        }
      }
    }

    // ---- publish partial gates (D layout: col=lane&31, row=(reg&3)+8*(reg>>2)+4*q2)
#pragma unroll
    for (int reg = 0; reg < 16; ++reg) {
      int b = (reg & 3) + 8 * (reg >> 2) + 4 * q2;
      gsc[(wk * 32 + b) * 64 + wn * 32 + col] = acc0[reg] + acc1[reg];
    }
    __syncthreads();

    // ---- LSTM cell update for my two (b, hid) pairs ----
    unsigned short hb2[2];
#pragma unroll
    for (int j = 0; j < 2; ++j) {
      int jl = jl_p + j;
      float4v ga = *(const float4v*)(gsc + b_p * 64 + jl * 4);          // K-half 0
      float4v gb = *(const float4v*)(gsc + (32 + b_p) * 64 + jl * 4);   // K-half 1
      float4v g = ga + gb + bias4[j];
      float i_ = 1.f / (1.f + __expf(-g[0]));
      float f_ = 1.f / (1.f + __expf(-g[1]));
      float gg = 2.f / (1.f + __expf(-2.f * g[2])) - 1.f;
      float o_ = 1.f / (1.f + __expf(-g[3]));
      float c = f_ * cst[j] + i_ * gg;
      cst[j] = c;
      float h = o_ * (2.f / (1.f + __expf(-2.f * c)) - 1.f);
      hb2[j] = f2bf(h);
    }
    {
      // write-through h store (2 bf16 packed in one dword, LLC-coherent)
      unsigned int hv = (unsigned int)hb2[0] | ((unsigned int)hb2[1] << 16);
      unsigned int* hdst = (unsigned int*)(hsout
          + ((size_t)(chain * 512 + tt) * 32 + b_p) * 512 + sl * 16 + jl_p);
      __hip_atomic_store(hdst, hv, __ATOMIC_RELAXED, __HIP_MEMORY_SCOPE_AGENT);
    }

    // ---- write prefetched x into the other LDS buffer (hides in drain) ----
    if (s < 511) {
      unsigned short* stxn = stx + (cur ^ 1) * 16640;
#pragma unroll
      for (int ii = 0; ii < 8; ++ii) {
        int n = tid + ii * 256;
        int r = n >> 6, c8 = n & 63;
        *(short8*)(stxn + r * 520 + c8 * 8) = xpre[ii];
      }
    }

    // drain my h store to the LLC, then barrier, then publish flag
    asm volatile("s_waitcnt vmcnt(0)" ::: "memory");
    __syncthreads();
    if (tid == 0)
      __hip_atomic_store(bar + (size_t)(chain * 32 + sl) * 32, (unsigned int)(s + 1),
                         __ATOMIC_RELAXED, __HIP_MEMORY_SCOPE_AGENT);
  }
}

// ---------------- gated combine --------------------------------------------
// comb[b][t][dd*512+k] = sum_e gate[b,e] * hs[e*2+dd][t][b][k]   (bf16 out)
__global__ void combine_kernel(const unsigned short* __restrict__ hs,
                               const float* __restrict__ gate,
                               unsigned short* __restrict__ comb) {
  int idx = blockIdx.x * 256 + threadIdx.x;     // 2,097,152 total
  int k8 = idx & 127, t = (idx >> 7) & 511, b = idx >> 16;
  int dd = k8 >> 6, kl = (k8 & 63) * 8;
  float a[8] = {0.f, 0.f, 0.f, 0.f, 0.f, 0.f, 0.f, 0.f};
#pragma unroll
  for (int e = 0; e < 4; ++e) {
    float g = gate[b * 4 + e];
    const unsigned short* src = hs + (size_t)(((e * 2 + dd) * 512 + t) * 32 + b) * 512 + kl;
    short8 v = *(const short8*)src;
#pragma unroll
    for (int r = 0; r < 8; ++r) a[r] += g * bf2f((unsigned short)v[r]);
  }
  short8 o;
#pragma unroll
  for (int r = 0; r < 8; ++r) o[r] = (short)f2bf(a[r]);
  *(short8*)(comb + (size_t)(b * 512 + t) * 1024 + k8 * 8) = o;
}

// ---------------- output projection GEMM -----------------------------------
// C[16384][512] = A(comb bf16 [16384][1024]) * Wout^T + bout, 128x128 tiles
__global__ __launch_bounds__(256) void gemm_out_kernel(
    const unsigned short* __restrict__ A, const unsigned short* __restrict__ Bw,
    const float* __restrict__ bout, float* __restrict__ out) {
  __shared__ unsigned short As[128 * 72];
  __shared__ unsigned short Bs[128 * 72];
  const int tid = threadIdx.x, wave = tid >> 6, lane = tid & 63;
  const int colg = lane & 15, qg = lane >> 4;
  const int m0 = blockIdx.x * 128, n0 = blockIdx.y * 128;
  const int wi = wave >> 1, wj = wave & 1;
  float4v z4 = {0.f, 0.f, 0.f, 0.f};
  float4v acc[4][4];
#pragma unroll
  for (int i = 0; i < 4; ++i)
#pragma unroll
    for (int j = 0; j < 4; ++j) acc[i][j] = z4;

  for (int k0 = 0; k0 < 1024; k0 += 64) {
#pragma unroll
    for (int ii = 0; ii < 4; ++ii) {
      int n = tid + ii * 256;                   // 1024 chunks of 16B
      int r = n >> 3, c8 = n & 7;
      short8 va = *(const short8*)(A  + (size_t)(m0 + r) * 1024 + k0 + c8 * 8);
      short8 vb = *(const short8*)(Bw + (size_t)(n0 + r) * 1024 + k0 + c8 * 8);
      *(short8*)(As + r * 72 + c8 * 8) = va;
      *(short8*)(Bs + r * 72 + c8 * 8) = vb;
    }
    __syncthreads();
#pragma unroll
    for (int kc = 0; kc < 2; ++kc) {
      short8 af[4], bf[4];
#pragma unroll
      for (int i = 0; i < 4; ++i)
        af[i] = *(const short8*)(As + (wi * 64 + i * 16 + colg) * 72 + kc * 32 + qg * 8);
#pragma unroll
      for (int j = 0; j < 4; ++j)
        bf[j] = *(const short8*)(Bs + (wj * 64 + j * 16 + colg) * 72 + kc * 32 + qg * 8);
#pragma unroll
      for (int i = 0; i < 4; ++i)
#pragma unroll
        for (int j = 0; j < 4; ++j)
          acc[i][j] = __builtin_amdgcn_mfma_f32_16x16x32_bf16(af[i], bf[j], acc[i][j], 0, 0, 0);
    }
    __syncthreads();
  }
#pragma unroll
  for (int j = 0; j < 4; ++j) {
    int n = n0 + wj * 64 + j * 16 + colg;
    float bo = bout[n];
#pragma unroll
    for (int i = 0; i < 4; ++i) {
      int mbase = m0 + wi * 64 + i * 16 + qg * 4;
#pragma unroll
      for (int r = 0; r < 4; ++r)
        out[(size_t)(mbase + r) * 512 + n] = acc[i][j][r] + bo;
    }
  }
}

// ---------------- host launcher --------------------------------------------

extern "C" void kernel_launch(void* const* d_in, const int* in_sizes, int n_in,
                              void* d_out, int out_size, void* d_ws, size_t ws_size,
                              hipStream_t stream) {
  (void)in_sizes; (void)n_in; (void)out_size; (void)ws_size;
  const float* x    = (const float*)d_in[0];
  const float* rW1  = (const float*)d_in[1];
  const float* rb1  = (const float*)d_in[2];
  const float* rW2  = (const float*)d_in[3];
  const float* rb2  = (const float*)d_in[4];
  const float* Wih  = (const float*)d_in[5];
  const float* Whh  = (const float*)d_in[6];
  const float* bih  = (const float*)d_in[7];
  const float* bhh  = (const float*)d_in[8];
  const float* Wout = (const float*)d_in[9];
  const float* bout = (const float*)d_in[10];
  float* out = (float*)d_out;

  char* ws = (char*)d_ws;
  size_t off = 0;
  auto alloc = [&](size_t bytes) -> char* {
    char* p = ws + off; off += (bytes + 255) & ~(size_t)255; return p;
  };
  unsigned short* xT     = (unsigned short*)alloc(16777216);   // [512][32][512] bf16
  unsigned short* Wp     = (unsigned short*)alloc(16777216);   // Wih permuted
  unsigned short* Up     = (unsigned short*)alloc(16777216);   // Whh permuted
  unsigned short* Wob    = (unsigned short*)alloc(1048576);    // Wout bf16
  float*          bias_p = (float*)alloc(65536);               // [8][2048]
  unsigned int*   bar    = (unsigned int*)alloc(32768);        // flags, 128B stride
  float*          gate   = (float*)alloc(512);                 // [32][4]
  float*          probs  = (float*)alloc(512);                 // [32][4]
  float*          rin    = (float*)alloc(65536);               // [32][512]
  unsigned short* hs     = (unsigned short*)alloc(134217728);  // [8][512][32][512]
  unsigned short* comb   = (unsigned short*)alloc(33554432);   // [16384][1024]

  // allow >64KB dynamic LDS for the persistent kernel
  (void)hipFuncSetAttribute((const void*)rnn_kernel,
                            hipFuncAttributeMaxDynamicSharedMemorySize, 116224);

  // zero the per-WG flag words
  hipMemsetAsync(bar, 0, 32768, stream);

  cx_kernel<<<4096, 256, 0, stream>>>(x, xT);
  cw_kernel<<<4096, 256, 0, stream>>>(Wih, Wp);
  cw_kernel<<<4096, 256, 0, stream>>>(Whh, Up);
  cwout_kernel<<<256, 256, 0, stream>>>(Wout, Wob);
  cbias_kernel<<<64, 256, 0, stream>>>(bih, bhh, bias_p);

  r1_kernel<<<64, 256, 0, stream>>>(x, rin);
  r2_kernel<<<32, 256, 0, stream>>>(rin, rW1, rb1, rW2, rb2, gate, probs);
  r3_kernel<<<1, 64, 0, stream>>>(probs, out + 8388608);

  rnn_kernel<<<256, 256, 116224, stream>>>(xT, Wp, Up, bias_p, hs, bar);

  combine_kernel<<<8192, 256, 0, stream>>>(hs, gate, comb);
  gemm_out_kernel<<<dim3(128, 4), 256, 0, stream>>>(comb, Wob, bout, out);
}